// Round 19
// baseline (446.826 us; speedup 1.0000x reference)
//
#include <hip/hip_runtime.h>

#define NPTS 4096
#define CH 64
#define BATCH 8
#define KNN 20
#define NEG_SLOPE 0.2f
#define EPSV 1e-5f
#define NEG_INF (-3.4e38f)

typedef float v2f __attribute__((ext_vector_type(2)));

// forced v_pk_fma_f32, src0 broadcast (R14, passed): aclo += (ap.lo)*b pair;
// achi += (ap.hi)*b pair. Each lane is an IEEE fma -> bit-identical chains.
__device__ __forceinline__ void fma2pair(v2f ap, v2f b, v2f& aclo, v2f& achi) {
  asm("v_pk_fma_f32 %0, %1, %2, %0 op_sel:[0,0,0] op_sel_hi:[0,1,1]"
      : "+v"(aclo) : "v"(ap), "v"(b));
  asm("v_pk_fma_f32 %0, %1, %2, %0 op_sel:[1,0,0] op_sel_hi:[1,1,1]"
      : "+v"(achi) : "v"(ap), "v"(b));
}

// v_pk_fma_f32, src1 broadcast-lo: acc.lo += ap.lo*wv.lo; acc.hi += ap.hi*wv.lo
// (two ROWS share one weight). Mirrors the R14-verified op_sel idiom.
__device__ __forceinline__ void fma2b1(v2f ap, v2f wv, v2f& acc) {
  asm("v_pk_fma_f32 %0, %1, %2, %0 op_sel:[0,0,0] op_sel_hi:[1,0,1]"
      : "+v"(acc) : "v"(ap), "v"(wv));
}

// ---------------- K2: P and xx ONLY (Q pathway deleted) ----------------
// Q was consumed solely by k_knn's epilogue at the block's own rows with the
// identical (row, o) thread mapping -> k_knn now computes q in-register.
// k_pq keeps the p chain (fmaf c ascending, via row-pair pk-fma where each
// lane is the same IEEE fma) and xx. W1 staged coalesced (c = lane),
// rsqrtf hoisted to 64/block (R18, passed).
__launch_bounds__(256, 4)
__global__ void k_pq(const float* __restrict__ x, const float* __restrict__ W,
                     const float* __restrict__ gamma, const float* __restrict__ rvar,
                     float* __restrict__ P, float* __restrict__ xx) {
  __shared__ float Ws1[CH * 65];   // [c][o] padded, W1*inv
  __shared__ float As[CH * 32];    // [c][n], 32 rows per block
  __shared__ float s_sh[64];
  int tid = threadIdx.x;
  int bid = blockIdx.x;
  int b = bid & 7, nb = bid >> 3;                  // XCD swizzle
  int n0 = nb * 32;
  const float* xb = x + (size_t)b * CH * NPTS;

  if (tid < 64) s_sh[tid] = gamma[tid] * rsqrtf(rvar[tid] + EPSV);
#pragma unroll
  for (int k = 0; k < 2; ++k) {
    int chunk = tid + 256 * k;                     // 0..511
    int c = chunk >> 3, cn = (chunk & 7) << 2;
    *(float4*)(As + c * 32 + cn) = *(const float4*)(xb + (size_t)c * NPTS + n0 + cn);
  }
  __syncthreads();                                 // s_sh ready

  for (int i = tid; i < CH * CH; i += 256) {
    int o = i >> 6, c = i & 63;                    // lane = c -> coalesced W
    Ws1[c * 65 + o] = W[o * 128 + c] * s_sh[o];
  }
  int o = tid & 63, w = tid >> 6;                  // lane = o; wave w
  __syncthreads();

  const float* Aw = As + 8 * w;                    // rows 8w..8w+7
  v2f pr[4];                                       // row pairs (0,1)..(6,7)
#pragma unroll
  for (int j = 0; j < 4; ++j) { pr[j].x = 0.f; pr[j].y = 0.f; }
#pragma unroll 4
  for (int c = 0; c < CH; ++c) {
    float4 A0 = *(const float4*)(Aw + c * 32);     // broadcast b128
    float4 A1 = *(const float4*)(Aw + c * 32 + 4);
    float w1 = Ws1[c * 65 + o];
    v2f wv; wv.x = w1; wv.y = w1;
    v2f a01; a01.x = A0.x; a01.y = A0.y;
    v2f a23; a23.x = A0.z; a23.y = A0.w;
    v2f a45; a45.x = A1.x; a45.y = A1.y;
    v2f a67; a67.x = A1.z; a67.y = A1.w;
    fma2b1(a01, wv, pr[0]);                        // p[r] += a[r]*w1 (IEEE)
    fma2b1(a23, wv, pr[1]);
    fma2b1(a45, wv, pr[2]);
    fma2b1(a67, wv, pr[3]);
  }
  float* Pb = P + ((size_t)b * NPTS + n0) * 64;
#pragma unroll
  for (int r = 0; r < 8; ++r) {
    int n = 8 * w + r;
    float pv = (r & 1) ? pr[r >> 1].y : pr[r >> 1].x;
    Pb[(size_t)n * 64 + o] = pv;                   // coalesced 256B store
  }
  if (w == 0 && o < 32) {                          // xx: same fmaf(v,v) chain
    float accx = 0.f;
#pragma unroll 8
    for (int c = 0; c < CH; ++c) {
      float v = As[c * 32 + o];
      accx = fmaf(v, v, accx);
    }
    xx[(size_t)b * NPTS + n0 + o] = accx;
  }
}

// ---------------- K1 helpers (R5-R18, passed) ----------------
__device__ __forceinline__ void insert_group(float d, int mg, int lane,
                                             float& vr, int& ir, float& th) {
  unsigned long long hit = __ballot(d > th);
  while (hit) {
    int j = __builtin_ctzll(hit);
    hit &= hit - 1;
    float cv = __shfl(d, j);
    int cm = mg + j;
    unsigned long long km = __ballot(vr >= cv);    // existing equals stay above
    int cnt = __popcll(km);
    float sv = __shfl_up(vr, 1);
    int si = __shfl_up(ir, 1);
    if (lane >= cnt) {
      vr = (lane == cnt) ? cv : sv;
      ir = (lane == cnt) ? cm : si;
    }
    th = __shfl(vr, KNN - 1);                      // refreshed 20th-best
    if (hit) hit &= __ballot(d > th);              // prune sub-threshold hits
  }
}

__device__ __forceinline__ void seed_sort(float d, int lane,
                                          float& vr, int& ir, float& th) {
  float v = d; int ix = lane;
#pragma unroll
  for (int k = 2; k <= 64; k <<= 1) {
#pragma unroll
    for (int j = k >> 1; j > 0; j >>= 1) {
      float pv = __shfl_xor(v, j);
      int   pi = __shfl_xor(ix, j);
      bool lower = (lane & j) == 0;
      bool desc  = (lane & k) == 0;                // block direction
      bool mineBefore = (v > pv) || (v == pv && ix < pi);
      bool keep = (mineBefore == (lower == desc));
      v  = keep ? v  : pv;
      ix = keep ? ix : pi;
    }
  }
  vr = v; ir = ix; th = __shfl(v, KNN - 1);
}

// GEMM (8 rows x 8 cols per thread) + register-direct selection.
// Verbatim R14/R16/R17/R18 (passed).
template <bool SEED>
__device__ __forceinline__ void tile_work(const float* __restrict__ bp,
                                          const float* As,
                                          const float* xxb, int m0, int w, int lane,
                                          const float (&xnr)[8],
                                          float (&val)[8], int (&idx)[8],
                                          float (&thd)[8]) {
  float xm[8];
#pragma unroll
  for (int g = 0; g < 8; ++g) xm[g] = xxb[m0 + 64 * g + lane];

  const float* Aw = As + 8 * w;                    // rows 8w..8w+7, LDA=64
  const float* bc = bp + m0;                       // per-lane: col m0+lane

  v2f acc[8][4];                                   // [row][col-pair]
#pragma unroll
  for (int r = 0; r < 8; ++r)
#pragma unroll
    for (int gp = 0; gp < 4; ++gp) { acc[r][gp].x = 0.f; acc[r][gp].y = 0.f; }

#pragma unroll 2
  for (int c = 0; c < CH; ++c) {
    float4 A0 = *(const float4*)(Aw + c * 64);       // rows 8w..8w+3 (broadcast)
    float4 A1 = *(const float4*)(Aw + c * 64 + 4);   // rows 8w+4..8w+7
    const float* bcc = bc + (size_t)c * NPTS;
    v2f bb[4];
    bb[0].x = bcc[0];    bb[0].y = bcc[64];          // cols m0+{0,64}+lane
    bb[1].x = bcc[128];  bb[1].y = bcc[192];
    bb[2].x = bcc[256];  bb[2].y = bcc[320];
    bb[3].x = bcc[384];  bb[3].y = bcc[448];
    v2f a01; a01.x = A0.x; a01.y = A0.y;
    v2f a23; a23.x = A0.z; a23.y = A0.w;
    v2f a45; a45.x = A1.x; a45.y = A1.y;
    v2f a67; a67.x = A1.z; a67.y = A1.w;
#pragma unroll
    for (int gp = 0; gp < 4; ++gp) {
      fma2pair(a01, bb[gp], acc[0][gp], acc[1][gp]);
      fma2pair(a23, bb[gp], acc[2][gp], acc[3][gp]);
      fma2pair(a45, bb[gp], acc[4][gp], acc[5][gp]);
      fma2pair(a67, bb[gp], acc[6][gp], acc[7][gp]);
    }
  }

#pragma unroll
  for (int r = 0; r < 8; ++r) {
#pragma unroll
    for (int gp = 0; gp < 4; ++gp) {
      float d0 = (2.f * acc[r][gp].x - xnr[r]) - xm[2 * gp];
      if (SEED && gp == 0) {
        seed_sort(d0, lane, val[r], idx[r], thd[r]);  // m0==0, g==0: col==lane
      } else {
        insert_group(d0, m0 + 128 * gp, lane, val[r], idx[r], thd[r]);
      }
      float d1 = (2.f * acc[r][gp].y - xnr[r]) - xm[2 * gp + 1];
      insert_group(d1, m0 + 128 * gp + 64, lane, val[r], idx[r], thd[r]);
    }
  }
}

// ---------------- K1: distance-GEMM + top-20 + fused output -----------------
// R16-R18 chassis + NEW prologue: compute q (the Q row of the old k_pq) for
// this block's own 64 rows in-register from the already-staged As tile and a
// Wsd LDS tile. Same fmaf chain (c ascending) and +shift -> q bits identical
// to the old global-Q round trip. LDS = S 16.6KB + Wsd 16.6KB + 0.5KB ->
// 2 blocks/CU unchanged.
__launch_bounds__(512, 4)
__global__ void k_knn(const float* __restrict__ x, const float* __restrict__ xx,
                      const float* __restrict__ P, const float* __restrict__ W,
                      const float* __restrict__ gamma, const float* __restrict__ beta,
                      const float* __restrict__ rmean, const float* __restrict__ rvar,
                      float* __restrict__ out) {
  __shared__ float S[64 * 65];                     // As uses first 64*64
  __shared__ float Wsd[64 * 65];                   // [c][o] padded
  __shared__ float s_sh[64], shift_sh[64];
  float* As = S;                                   // [c][n], LDA=64
  int tid = threadIdx.x;
  int bid = blockIdx.x;
  int b = bid & 7, nb = bid >> 3;                  // XCD-swizzled decode
  int n0 = nb * 64;
  const float* xb = x + (size_t)b * CH * NPTS;
  const float* xxb = xx + b * NPTS;
  int lane = tid & 63;
  int w = tid >> 6;                                // 0..7

  // stage A-tile [c][n]: 4096 floats, 512 threads x 8 floats
  {
    int c = tid >> 3, n8 = (tid & 7) << 3;
    float4 v0 = *(const float4*)(xb + (size_t)c * NPTS + n0 + n8);
    float4 v1 = *(const float4*)(xb + (size_t)c * NPTS + n0 + n8 + 4);
    *(float4*)(As + c * 64 + n8) = v0;
    *(float4*)(As + c * 64 + n8 + 4) = v1;
  }
  if (tid < 64) {
    float s = gamma[tid] * rsqrtf(rvar[tid] + EPSV);
    s_sh[tid] = s;
    shift_sh[tid] = beta[tid] - rmean[tid] * s;
  }
  __syncthreads();                                 // As + s_sh ready

  // stage Wsd coalesced (lane = c): (w2-w1)*s — same arithmetic as old k_pq
  for (int i = tid; i < CH * CH; i += 512) {
    int o = i >> 6, c = i & 63;
    float w1 = W[o * 128 + c], w2 = W[o * 128 + 64 + c];
    Wsd[c * 65 + o] = (w2 - w1) * s_sh[o];
  }
  __syncthreads();                                 // Wsd ready

  // q for own rows 8w..8w+7, channel o = lane (same chain as old accq)
  float qv[8];
  {
    const float* Aw = As + 8 * w;
    v2f qr[4];
#pragma unroll
    for (int j = 0; j < 4; ++j) { qr[j].x = 0.f; qr[j].y = 0.f; }
#pragma unroll 4
    for (int c = 0; c < CH; ++c) {
      float4 A0 = *(const float4*)(Aw + c * 64);
      float4 A1 = *(const float4*)(Aw + c * 64 + 4);
      float wd = Wsd[c * 65 + lane];
      v2f wv; wv.x = wd; wv.y = wd;
      v2f a01; a01.x = A0.x; a01.y = A0.y;
      v2f a23; a23.x = A0.z; a23.y = A0.w;
      v2f a45; a45.x = A1.x; a45.y = A1.y;
      v2f a67; a67.x = A1.z; a67.y = A1.w;
      fma2b1(a01, wv, qr[0]);
      fma2b1(a23, wv, qr[1]);
      fma2b1(a45, wv, qr[2]);
      fma2b1(a67, wv, qr[3]);
    }
    float shift = shift_sh[lane];
#pragma unroll
    for (int r = 0; r < 8; ++r)
      qv[r] = ((r & 1) ? qr[r >> 1].y : qr[r >> 1].x) + shift;
  }

  float xnr[8];
#pragma unroll
  for (int r = 0; r < 8; ++r) xnr[r] = xxb[n0 + 8 * w + r];

  float val[8]; int idx[8]; float thd[8];
#pragma unroll
  for (int r = 0; r < 8; ++r) { val[r] = NEG_INF; idx[r] = 0; thd[r] = NEG_INF; }

  const float* bp = xb + lane;                     // per-lane B base

  // chunk 0: seeded selection
  tile_work<true>(bp, As, xxb, 0, w, lane, xnr, val, idx, thd);

#pragma unroll 1
  for (int mt = 1; mt < NPTS / 512; ++mt)
    tile_work<false>(bp, As, xxb, mt * 512, w, lane, xnr, val, idx, thd);

  // ---- fused output epilogue (q from registers; same op order) ----
  const float* Pb = P + (size_t)b * NPTS * 64;
  __syncthreads();                                 // all As readers done
#pragma unroll
  for (int r = 0; r < 8; ++r) {
    float mx = NEG_INF;
#pragma unroll
    for (int k = 0; k < KNN; ++k) {                // k ascending == old ip[k]
      int id = __shfl(idx[r], k);
      mx = fmaxf(mx, Pb[(size_t)id * 64 + lane]);  // coalesced 256B line
    }
    float z = mx + qv[r];                          // == old mx + Q[n][lane]
    z = (z >= 0.f) ? z : NEG_SLOPE * z;
    S[lane * 65 + 8 * w + r] = z;                  // stride 65: conflict-free
  }
  __syncthreads();
  float* ob = out + (size_t)b * 64 * NPTS + n0;
#pragma unroll
  for (int r = 0; r < 8; ++r) {
    int o = 8 * w + r;
    ob[(size_t)o * NPTS + lane] = S[o * 65 + lane]; // coalesced 256B store
  }
}

extern "C" void kernel_launch(void* const* d_in, const int* in_sizes, int n_in,
                              void* d_out, int out_size, void* d_ws, size_t ws_size,
                              hipStream_t stream) {
  const float* x     = (const float*)d_in[0];
  const float* W     = (const float*)d_in[1];
  const float* gamma = (const float*)d_in[2];
  const float* beta  = (const float*)d_in[3];
  const float* rmean = (const float*)d_in[4];
  const float* rvar  = (const float*)d_in[5];
  float* out = (float*)d_out;

  float* xx = (float*)d_ws;                        // 32768 floats
  float* P  = xx + 32768;                          // 2097152 floats

  k_pq<<<BATCH * NPTS / 32, 256, 0, stream>>>(x, W, gamma, rvar, P, xx);
  k_knn<<<BATCH * NPTS / 64, 512, 0, stream>>>(x, xx, P, W, gamma, beta,
                                               rmean, rvar, out);
}

// Round 20
// 429.630 us; speedup vs baseline: 1.0400x; 1.0400x over previous
//
#include <hip/hip_runtime.h>

#define NPTS 4096
#define CH 64
#define BATCH 8
#define KNN 20
#define NEG_SLOPE 0.2f
#define EPSV 1e-5f
#define NEG_INF (-3.4e38f)

typedef float v2f __attribute__((ext_vector_type(2)));

// forced v_pk_fma_f32, src0 broadcast (R14, passed): aclo += (ap.lo)*b pair;
// achi += (ap.hi)*b pair. Each lane is an IEEE fma -> bit-identical chains.
__device__ __forceinline__ void fma2pair(v2f ap, v2f b, v2f& aclo, v2f& achi) {
  asm("v_pk_fma_f32 %0, %1, %2, %0 op_sel:[0,0,0] op_sel_hi:[0,1,1]"
      : "+v"(aclo) : "v"(ap), "v"(b));
  asm("v_pk_fma_f32 %0, %1, %2, %0 op_sel:[1,0,0] op_sel_hi:[1,1,1]"
      : "+v"(achi) : "v"(ap), "v"(b));
}

// v_pk_fma_f32, src1 broadcast-lo: acc.lo += ap.lo*wv.lo; acc.hi += ap.hi*wv.lo
// (two ROWS share one weight). R18/R19-verified op_sel idiom.
__device__ __forceinline__ void fma2b1(v2f ap, v2f wv, v2f& acc) {
  asm("v_pk_fma_f32 %0, %1, %2, %0 op_sel:[0,0,0] op_sel_hi:[1,0,1]"
      : "+v"(acc) : "v"(ap), "v"(wv));
}

// ---------------- K2: P and xx ONLY (R19, passed at ~30us) ----------------
__launch_bounds__(256, 4)
__global__ void k_pq(const float* __restrict__ x, const float* __restrict__ W,
                     const float* __restrict__ gamma, const float* __restrict__ rvar,
                     float* __restrict__ P, float* __restrict__ xx) {
  __shared__ float Ws1[CH * 65];   // [c][o] padded, W1*inv
  __shared__ float As[CH * 32];    // [c][n], 32 rows per block
  __shared__ float s_sh[64];
  int tid = threadIdx.x;
  int bid = blockIdx.x;
  int b = bid & 7, nb = bid >> 3;                  // XCD swizzle
  int n0 = nb * 32;
  const float* xb = x + (size_t)b * CH * NPTS;

  if (tid < 64) s_sh[tid] = gamma[tid] * rsqrtf(rvar[tid] + EPSV);
#pragma unroll
  for (int k = 0; k < 2; ++k) {
    int chunk = tid + 256 * k;                     // 0..511
    int c = chunk >> 3, cn = (chunk & 7) << 2;
    *(float4*)(As + c * 32 + cn) = *(const float4*)(xb + (size_t)c * NPTS + n0 + cn);
  }
  __syncthreads();                                 // s_sh ready

  for (int i = tid; i < CH * CH; i += 256) {
    int o = i >> 6, c = i & 63;                    // lane = c -> coalesced W
    Ws1[c * 65 + o] = W[o * 128 + c] * s_sh[o];
  }
  int o = tid & 63, w = tid >> 6;                  // lane = o; wave w
  __syncthreads();

  const float* Aw = As + 8 * w;                    // rows 8w..8w+7
  v2f pr[4];                                       // row pairs (0,1)..(6,7)
#pragma unroll
  for (int j = 0; j < 4; ++j) { pr[j].x = 0.f; pr[j].y = 0.f; }
#pragma unroll 4
  for (int c = 0; c < CH; ++c) {
    float4 A0 = *(const float4*)(Aw + c * 32);     // broadcast b128
    float4 A1 = *(const float4*)(Aw + c * 32 + 4);
    float w1 = Ws1[c * 65 + o];
    v2f wv; wv.x = w1; wv.y = w1;
    v2f a01; a01.x = A0.x; a01.y = A0.y;
    v2f a23; a23.x = A0.z; a23.y = A0.w;
    v2f a45; a45.x = A1.x; a45.y = A1.y;
    v2f a67; a67.x = A1.z; a67.y = A1.w;
    fma2b1(a01, wv, pr[0]);                        // p[r] += a[r]*w1 (IEEE)
    fma2b1(a23, wv, pr[1]);
    fma2b1(a45, wv, pr[2]);
    fma2b1(a67, wv, pr[3]);
  }
  float* Pb = P + ((size_t)b * NPTS + n0) * 64;
#pragma unroll
  for (int r = 0; r < 8; ++r) {
    int n = 8 * w + r;
    float pv = (r & 1) ? pr[r >> 1].y : pr[r >> 1].x;
    Pb[(size_t)n * 64 + o] = pv;                   // coalesced 256B store
  }
  if (w == 0 && o < 32) {                          // xx: same fmaf(v,v) chain
    float accx = 0.f;
#pragma unroll 8
    for (int c = 0; c < CH; ++c) {
      float v = As[c * 32 + o];
      accx = fmaf(v, v, accx);
    }
    xx[(size_t)b * NPTS + n0 + o] = accx;
  }
}

// ---------------- K1 helpers (R5-R18, passed) ----------------
__device__ __forceinline__ void insert_group(float d, int mg, int lane,
                                             float& vr, int& ir, float& th) {
  unsigned long long hit = __ballot(d > th);
  while (hit) {
    int j = __builtin_ctzll(hit);
    hit &= hit - 1;
    float cv = __shfl(d, j);
    int cm = mg + j;
    unsigned long long km = __ballot(vr >= cv);    // existing equals stay above
    int cnt = __popcll(km);
    float sv = __shfl_up(vr, 1);
    int si = __shfl_up(ir, 1);
    if (lane >= cnt) {
      vr = (lane == cnt) ? cv : sv;
      ir = (lane == cnt) ? cm : si;
    }
    th = __shfl(vr, KNN - 1);                      // refreshed 20th-best
    if (hit) hit &= __ballot(d > th);              // prune sub-threshold hits
  }
}

__device__ __forceinline__ void seed_sort(float d, int lane,
                                          float& vr, int& ir, float& th) {
  float v = d; int ix = lane;
#pragma unroll
  for (int k = 2; k <= 64; k <<= 1) {
#pragma unroll
    for (int j = k >> 1; j > 0; j >>= 1) {
      float pv = __shfl_xor(v, j);
      int   pi = __shfl_xor(ix, j);
      bool lower = (lane & j) == 0;
      bool desc  = (lane & k) == 0;                // block direction
      bool mineBefore = (v > pv) || (v == pv && ix < pi);
      bool keep = (mineBefore == (lower == desc));
      v  = keep ? v  : pv;
      ix = keep ? ix : pi;
    }
  }
  vr = v; ir = ix; th = __shfl(v, KNN - 1);
}

// GEMM (8 rows x 8 cols per thread) + register-direct selection.
// Verbatim R14-R19 (passed).
template <bool SEED>
__device__ __forceinline__ void tile_work(const float* __restrict__ bp,
                                          const float* As,
                                          const float* xxb, int m0, int w, int lane,
                                          const float (&xnr)[8],
                                          float (&val)[8], int (&idx)[8],
                                          float (&thd)[8]) {
  float xm[8];
#pragma unroll
  for (int g = 0; g < 8; ++g) xm[g] = xxb[m0 + 64 * g + lane];

  const float* Aw = As + 8 * w;                    // rows 8w..8w+7, LDA=64
  const float* bc = bp + m0;                       // per-lane: col m0+lane

  v2f acc[8][4];                                   // [row][col-pair]
#pragma unroll
  for (int r = 0; r < 8; ++r)
#pragma unroll
    for (int gp = 0; gp < 4; ++gp) { acc[r][gp].x = 0.f; acc[r][gp].y = 0.f; }

#pragma unroll 2
  for (int c = 0; c < CH; ++c) {
    float4 A0 = *(const float4*)(Aw + c * 64);       // rows 8w..8w+3 (broadcast)
    float4 A1 = *(const float4*)(Aw + c * 64 + 4);   // rows 8w+4..8w+7
    const float* bcc = bc + (size_t)c * NPTS;
    v2f bb[4];
    bb[0].x = bcc[0];    bb[0].y = bcc[64];          // cols m0+{0,64}+lane
    bb[1].x = bcc[128];  bb[1].y = bcc[192];
    bb[2].x = bcc[256];  bb[2].y = bcc[320];
    bb[3].x = bcc[384];  bb[3].y = bcc[448];
    v2f a01; a01.x = A0.x; a01.y = A0.y;
    v2f a23; a23.x = A0.z; a23.y = A0.w;
    v2f a45; a45.x = A1.x; a45.y = A1.y;
    v2f a67; a67.x = A1.z; a67.y = A1.w;
#pragma unroll
    for (int gp = 0; gp < 4; ++gp) {
      fma2pair(a01, bb[gp], acc[0][gp], acc[1][gp]);
      fma2pair(a23, bb[gp], acc[2][gp], acc[3][gp]);
      fma2pair(a45, bb[gp], acc[4][gp], acc[5][gp]);
      fma2pair(a67, bb[gp], acc[6][gp], acc[7][gp]);
    }
  }

#pragma unroll
  for (int r = 0; r < 8; ++r) {
#pragma unroll
    for (int gp = 0; gp < 4; ++gp) {
      float d0 = (2.f * acc[r][gp].x - xnr[r]) - xm[2 * gp];
      if (SEED && gp == 0) {
        seed_sort(d0, lane, val[r], idx[r], thd[r]);  // m0==0, g==0: col==lane
      } else {
        insert_group(d0, m0 + 128 * gp, lane, val[r], idx[r], thd[r]);
      }
      float d1 = (2.f * acc[r][gp].y - xnr[r]) - xm[2 * gp + 1];
      insert_group(d1, m0 + 128 * gp + 64, lane, val[r], idx[r], thd[r]);
    }
  }
}

// ---------------- K1: distance-GEMM + top-20 + fused output -----------------
// R18 chassis + q-fusion with q parked in LDS (fixes R19's register spill):
// the Wsd staging tile is dead after the q-prologue -> reuse it to hold the
// block's 512x8 q values. The main loop carries ZERO extra live registers
// (identical regalloc situation to R18); the epilogue reads q back with 8
// conflict-free ds_read_b32. Same fmaf chains and +shift -> bit-identical.
__launch_bounds__(512, 4)
__global__ void k_knn(const float* __restrict__ x, const float* __restrict__ xx,
                      const float* __restrict__ P, const float* __restrict__ W,
                      const float* __restrict__ gamma, const float* __restrict__ beta,
                      const float* __restrict__ rmean, const float* __restrict__ rvar,
                      float* __restrict__ out) {
  __shared__ float S[64 * 65];                     // As uses first 64*64
  __shared__ float Wsd[64 * 65];                   // [c][o] padded; reused for q
  __shared__ float s_sh[64], shift_sh[64];
  float* As = S;                                   // [c][n], LDA=64
  float* qLds = Wsd;                               // [r][tid] after prologue
  int tid = threadIdx.x;
  int bid = blockIdx.x;
  int b = bid & 7, nb = bid >> 3;                  // XCD-swizzled decode
  int n0 = nb * 64;
  const float* xb = x + (size_t)b * CH * NPTS;
  const float* xxb = xx + b * NPTS;
  int lane = tid & 63;
  int w = tid >> 6;                                // 0..7

  // stage A-tile [c][n]: 4096 floats, 512 threads x 8 floats
  {
    int c = tid >> 3, n8 = (tid & 7) << 3;
    float4 v0 = *(const float4*)(xb + (size_t)c * NPTS + n0 + n8);
    float4 v1 = *(const float4*)(xb + (size_t)c * NPTS + n0 + n8 + 4);
    *(float4*)(As + c * 64 + n8) = v0;
    *(float4*)(As + c * 64 + n8 + 4) = v1;
  }
  if (tid < 64) {
    float s = gamma[tid] * rsqrtf(rvar[tid] + EPSV);
    s_sh[tid] = s;
    shift_sh[tid] = beta[tid] - rmean[tid] * s;
  }
  __syncthreads();                                 // As + s_sh ready

  // stage Wsd coalesced (lane = c): (w2-w1)*s — same arithmetic as old k_pq
  for (int i = tid; i < CH * CH; i += 512) {
    int o = i >> 6, c = i & 63;
    float w1 = W[o * 128 + c], w2 = W[o * 128 + 64 + c];
    Wsd[c * 65 + o] = (w2 - w1) * s_sh[o];
  }
  __syncthreads();                                 // Wsd ready

  // q for own rows 8w..8w+7, channel o = lane (same chain as old accq)
  {
    const float* Aw = As + 8 * w;
    v2f qr[4];
#pragma unroll
    for (int j = 0; j < 4; ++j) { qr[j].x = 0.f; qr[j].y = 0.f; }
#pragma unroll 4
    for (int c = 0; c < CH; ++c) {
      float4 A0 = *(const float4*)(Aw + c * 64);
      float4 A1 = *(const float4*)(Aw + c * 64 + 4);
      float wd = Wsd[c * 65 + lane];
      v2f wv; wv.x = wd; wv.y = wd;
      v2f a01; a01.x = A0.x; a01.y = A0.y;
      v2f a23; a23.x = A0.z; a23.y = A0.w;
      v2f a45; a45.x = A1.x; a45.y = A1.y;
      v2f a67; a67.x = A1.z; a67.y = A1.w;
      fma2b1(a01, wv, qr[0]);
      fma2b1(a23, wv, qr[1]);
      fma2b1(a45, wv, qr[2]);
      fma2b1(a67, wv, qr[3]);
    }
    float shift = shift_sh[lane];
    __syncthreads();                               // all Wsd readers done
#pragma unroll
    for (int r = 0; r < 8; ++r)                    // stash q in dead Wsd region
      qLds[r * 512 + tid] =
          ((r & 1) ? qr[r >> 1].y : qr[r >> 1].x) + shift;  // conflict-free
  }

  float xnr[8];
#pragma unroll
  for (int r = 0; r < 8; ++r) xnr[r] = xxb[n0 + 8 * w + r];

  float val[8]; int idx[8]; float thd[8];
#pragma unroll
  for (int r = 0; r < 8; ++r) { val[r] = NEG_INF; idx[r] = 0; thd[r] = NEG_INF; }

  const float* bp = xb + lane;                     // per-lane B base

  // chunk 0: seeded selection
  tile_work<true>(bp, As, xxb, 0, w, lane, xnr, val, idx, thd);

#pragma unroll 1
  for (int mt = 1; mt < NPTS / 512; ++mt)
    tile_work<false>(bp, As, xxb, mt * 512, w, lane, xnr, val, idx, thd);

  // ---- fused output epilogue (q from LDS; same op order -> bit-exact) ----
  const float* Pb = P + (size_t)b * NPTS * 64;
  __syncthreads();                                 // all As readers done
#pragma unroll
  for (int r = 0; r < 8; ++r) {
    float mx = NEG_INF;
#pragma unroll
    for (int k = 0; k < KNN; ++k) {                // k ascending == old ip[k]
      int id = __shfl(idx[r], k);
      mx = fmaxf(mx, Pb[(size_t)id * 64 + lane]);  // coalesced 256B line
    }
    float z = mx + qLds[r * 512 + tid];            // == old mx + Q[n][lane]
    z = (z >= 0.f) ? z : NEG_SLOPE * z;
    S[lane * 65 + 8 * w + r] = z;                  // stride 65: conflict-free
  }
  __syncthreads();
  float* ob = out + (size_t)b * 64 * NPTS + n0;
#pragma unroll
  for (int r = 0; r < 8; ++r) {
    int o = 8 * w + r;
    ob[(size_t)o * NPTS + lane] = S[o * 65 + lane]; // coalesced 256B store
  }
}

extern "C" void kernel_launch(void* const* d_in, const int* in_sizes, int n_in,
                              void* d_out, int out_size, void* d_ws, size_t ws_size,
                              hipStream_t stream) {
  const float* x     = (const float*)d_in[0];
  const float* W     = (const float*)d_in[1];
  const float* gamma = (const float*)d_in[2];
  const float* beta  = (const float*)d_in[3];
  const float* rmean = (const float*)d_in[4];
  const float* rvar  = (const float*)d_in[5];
  float* out = (float*)d_out;

  float* xx = (float*)d_ws;                        // 32768 floats
  float* P  = xx + 32768;                          // 2097152 floats

  k_pq<<<BATCH * NPTS / 32, 256, 0, stream>>>(x, W, gamma, rvar, P, xx);
  k_knn<<<BATCH * NPTS / 64, 512, 0, stream>>>(x, xx, P, W, gamma, beta,
                                               rmean, rvar, out);
}